// Round 6
// baseline (12032.851 us; speedup 1.0000x reference)
//
#include <hip/hip_runtime.h>
#include <math.h>

#define B_    32
#define S_    512
#define EMB_  512
#define HID_  1024
#define LAB_  64
#define M_    (B_ * S_)

// ---------------------------------------------------------------------------
// R15: FUSED two-layer skewed pipeline. 256 WGs x 512 threads, 1 WG/CU.
// Partition: slice s = wg>>3 (32 slices x 32 neurons), group g = wg&7
// (8 groups x 4 batches). Each WG handles BOTH layers for its (slice,group).
//
// Pipeline (round r = 0..512):
//   layer-0 step r   (r<512): h0(r) = tanh(xp0(r) + Whh0 h0(r-1))
//   layer-1 step r-1 (r>=1):  h1(r-1) = tanh(Wih1 h0(r-1) + Whh1 h1(r-2) + b)
// Both consumed vectors (h0(r-1), h1(r-2)) were published at round r-1 ->
// uniform 1-round skew, ONE poll phase + ONE barrier per round. Serial
// handshake count drops 1024 -> 513, and the xp1 GEMM disappears (computed
// in-pipeline from the staged h0). h1 overwrites consumed xp0 in place:
// cell (b,t,n) is read (xp0) at round t and written (h1) at round t+1 by
// the same owner lane.
//
// Exchange (R14 epoch protocol, two regions):
//   word = u64 {enc(h[2c]) lo, enc(h[2c+1]) hi}, enc = bits|((r>>2)&1)<<30
//   (tanh output => bit30 always 0). Layout:
//   ex[(L*4+slot)*16384 + g*2048 + c*1024 + n], 131072 u64 = 1 MB in d_out.
//   Publish at round r -> slot r&3; consume at round r -> slot (r-1)&3 with
//   epoch ((r-1)>>2)&1. Skew<=1 (staging r requires ALL publishes r-1) =>
//   only possible stale content is 4 rounds old = opposite epoch. Startup:
//   every address's FIRST poll expects epoch 0 except L1 slot 0 (first
//   polled at round 5 with epoch 1, first published at round 4) -> fill L1
//   slot 0 with an epoch-0-looking pattern, everything else epoch-1-looking.
//   After the first accepted read, per-location coherence forbids regressing
//   to the fill.
//
// History: R9 single-hop tagged = 7.9k cyc/step; R11 flag hop +RTs = worse;
// R12 L2-local = coherence pathology; R14 epoch words = 7.2k/step (latency-
// floor bound, traffic reduction exhausted). R15 attacks the handshake COUNT.
// ---------------------------------------------------------------------------
#define SLOT_U64   2048                   // per (layer,slot,group)
#define LS_STRIDE  (8 * SLOT_U64)         // per (layer,slot)
#define EX_TOTAL   (2 * 4 * LS_STRIDE)    // 131072 u64 = 1 MB
#define EPMASK64   0x4000000040000000ULL
#define NANPAT64   0x7FC000007FC00000ULL  // epoch-1-looking fill
#define ONEPAT64   0x3F8000003F800000ULL  // epoch-0-looking fill (L1 slot 0)
#define PAYMASK    0xBFFFFFFFu

__device__ __forceinline__ unsigned long long aload64(const unsigned long long* p) {
    return __hip_atomic_load((unsigned long long*)p, __ATOMIC_RELAXED,
                             __HIP_MEMORY_SCOPE_AGENT);
}
__device__ __forceinline__ void astore64(unsigned long long* p, unsigned long long v) {
    __hip_atomic_store(p, v, __ATOMIC_RELAXED, __HIP_MEMORY_SCOPE_AGENT);
}

// ---------------------------------------------------------------------------
// fp32 tiled GEMM (unchanged): BM=128, BN=64, BK=16, 256 thr, 8x4/thread.
// ---------------------------------------------------------------------------
__global__ __launch_bounds__(256) void gemm_bias(
    const float* __restrict__ A, const int* __restrict__ tokens,
    const float* __restrict__ W, const float* __restrict__ bias,
    const float* __restrict__ bias2, float* __restrict__ C,
    int M, int K, int N)
{
    __shared__ float As[128][17];
    __shared__ float Ws[64][17];

    const int tid = threadIdx.x;
    const int tx  = tid & 15;
    const int ty  = tid >> 4;
    const int n0  = blockIdx.x * 64;
    const int m0  = blockIdx.y * 128;

    const int lr  = tid >> 2;
    const int lk  = (tid & 3) << 2;

    const int ar0 = tokens ? tokens[m0 + lr]      : (m0 + lr);
    const int ar1 = tokens ? tokens[m0 + 64 + lr] : (m0 + 64 + lr);
    const float* __restrict__ arow0 = A + (size_t)ar0 * K;
    const float* __restrict__ arow1 = A + (size_t)ar1 * K;
    const float* __restrict__ wrow  = W + (size_t)(n0 + lr) * K;

    float bs[4];
#pragma unroll
    for (int j = 0; j < 4; ++j) {
        int n = n0 + tx * 4 + j;
        bs[j] = bias[n] + (bias2 ? bias2[n] : 0.0f);
    }

    float acc[8][4] = {};

    for (int k0 = 0; k0 < K; k0 += 16) {
        const float4 a0 = *(const float4*)(arow0 + k0 + lk);
        const float4 a1 = *(const float4*)(arow1 + k0 + lk);
        const float4 wv = *(const float4*)(wrow  + k0 + lk);
        __syncthreads();
        As[lr][lk + 0] = a0.x; As[lr][lk + 1] = a0.y;
        As[lr][lk + 2] = a0.z; As[lr][lk + 3] = a0.w;
        As[64 + lr][lk + 0] = a1.x; As[64 + lr][lk + 1] = a1.y;
        As[64 + lr][lk + 2] = a1.z; As[64 + lr][lk + 3] = a1.w;
        Ws[lr][lk + 0] = wv.x; Ws[lr][lk + 1] = wv.y;
        Ws[lr][lk + 2] = wv.z; Ws[lr][lk + 3] = wv.w;
        __syncthreads();

#pragma unroll
        for (int kk = 0; kk < 16; ++kk) {
            float b[4], a[8];
#pragma unroll
            for (int j = 0; j < 4; ++j) b[j] = Ws[tx * 4 + j][kk];
#pragma unroll
            for (int i = 0; i < 8; ++i) a[i] = As[ty * 8 + i][kk];
#pragma unroll
            for (int i = 0; i < 8; ++i)
#pragma unroll
                for (int j = 0; j < 4; ++j)
                    acc[i][j] += a[i] * b[j];
        }
    }

#pragma unroll
    for (int i = 0; i < 8; ++i) {
        const int m = m0 + ty * 8 + i;
        float4 v;
        v.x = acc[i][0] + bs[0];
        v.y = acc[i][1] + bs[1];
        v.z = acc[i][2] + bs[2];
        v.w = acc[i][3] + bs[3];
        *(float4*)(C + (size_t)m * N + n0 + tx * 4) = v;
    }
}

// ---------------------------------------------------------------------------
// Fill: NANPAT (epoch-1-look) everywhere except L1 slot 0 (ls index 4).
// ---------------------------------------------------------------------------
__global__ __launch_bounds__(256) void fill_poison(unsigned long long* p, int n)
{
    const int i = blockIdx.x * 256 + threadIdx.x;
    if (i < n) {
        const int ls = i / LS_STRIDE;          // layer*4 + slot
        p[i] = (ls == 4) ? ONEPAT64 : NANPAT64;
    }
}

// ---------------------------------------------------------------------------
// Fused 2-layer skewed scan. Weights: 3 slices x (4 n x 16 q) = 192 VGPRs.
// LDS: 4 planes (h0/h1 x double-buffer) x 2048 float2 = 64 KB. One barrier
// per round; double-buffer safety: reads of plane[r&1] (post-barrier r)
// finish before this thread's barrier(r+1); any overwrite of plane[r&1]
// (staging of round r+2) happens after barrier(r+1).
// 16-acc tree: lane p ends holding out(p&15), a = i*4+b.
// ---------------------------------------------------------------------------
__global__ __launch_bounds__(512, 2) void rnn_fused(
    const float* __restrict__ Whh0, const float* __restrict__ Whh1,
    const float* __restrict__ Wih1, const float* __restrict__ b_ih1,
    const float* __restrict__ b_hh1, float* __restrict__ xb,
    unsigned long long* __restrict__ ex)
{
    extern __shared__ float smem[];
    float2* hb = (float2*)smem;        // [2 layer][2 buf][2048] float2

    const int wg  = blockIdx.x;
    const int g   = wg & 7;            // group: batches g*4..g*4+3
    const int s   = wg >> 3;           // slice: neurons s*32..s*32+31
    const int tid = threadIdx.x;       // 0..511
    const int j8  = tid >> 6;          // wave: neurons s*32 + j8*4 ..+3
    const int kg  = tid & 63;          // lane; k = kg + 64q
    const int b0  = g * 4;

    // weights: 4 neurons x 16 strided k, three matrices (lane-coalesced)
    float w0[4][16], wx[4][16], wh[4][16];
    {
        const size_t base = (size_t)(s * 32 + j8 * 4) * HID_ + kg;
#pragma unroll
        for (int i = 0; i < 4; ++i)
#pragma unroll
            for (int q = 0; q < 16; ++q) {
                const size_t o = base + (size_t)i * HID_ + (size_t)q * 64;
                w0[i][q] = Whh0[o];
                wx[i][q] = Wih1[o];
                wh[i][q] = Whh1[o];
            }
    }

    const int i4 = (kg >> 2) & 3;      // output neuron (lanes<16)
    const int bb = kg & 3;             // output batch  (lanes<16)
    const int ok = s * 32 + j8 * 4 + i4;
    float bsum = 0.f;
    if (kg < 16) bsum = b_ih1[ok] + b_hh1[ok];

    float* px0 = xb + ((size_t)(b0 + bb) * S_) * HID_ + ok;  // xp0 read (b,r)
    float* px1 = px0;                                        // h1 write (b,r-1)

    unsigned long long* const exg = ex + (size_t)g * SLOT_U64;

    for (int r = 0; r <= S_; ++r) {
        // ---- xp0 prefetch (overlaps the poll) ----
        float xpv = 0.f;
        if (kg < 16 && r < S_) xpv = *px0;
        px0 += HID_;

        const int cur = r & 1;
        float2* s0 = hb + (size_t)cur * 2048;          // h0(r-1) plane
        float2* s1 = hb + (size_t)(2 + cur) * 2048;    // h1(r-2) plane

        // ---- stage: poll both regions' slot (r-1)&3 with its epoch ----
        if (r == 0) {
#pragma unroll
            for (int k = 0; k < 4; ++k) {
                s0[tid + 512 * k] = make_float2(0.f, 0.f);
                s1[tid + 512 * k] = make_float2(0.f, 0.f);
            }
        } else {
            const int sl = (r - 1) & 3;
            const unsigned long long want =
                (((unsigned)(r - 1) >> 2) & 1u) ? EPMASK64 : 0ULL;
            const unsigned long long* pl0 = exg + (size_t)sl * LS_STRIDE;
            const unsigned long long* pl1 = exg + (size_t)(4 + sl) * LS_STRIDE;
            unsigned long long d[8];
            unsigned pend = (r >= 2) ? 0xFFu : 0x0Fu;
            if (r == 1) {
#pragma unroll
                for (int k = 0; k < 4; ++k)
                    s1[tid + 512 * k] = make_float2(0.f, 0.f);
            }
            do {
#pragma unroll
                for (int k = 0; k < 4; ++k) {
                    if (pend & (1u << k)) {
                        const unsigned long long u = aload64(pl0 + tid + 512 * k);
                        if ((u & EPMASK64) == want) { d[k] = u; pend &= ~(1u << k); }
                    }
                    if (pend & (1u << (4 + k))) {
                        const unsigned long long u = aload64(pl1 + tid + 512 * k);
                        if ((u & EPMASK64) == want) { d[4+k] = u; pend &= ~(1u << (4+k)); }
                    }
                }
            } while (pend);
#pragma unroll
            for (int k = 0; k < 4; ++k) {
                const unsigned long long u = d[k];
                s0[tid + 512 * k] = make_float2(
                    __uint_as_float((unsigned)u & PAYMASK),
                    __uint_as_float((unsigned)(u >> 32) & PAYMASK));
            }
            if (r >= 2) {
#pragma unroll
                for (int k = 0; k < 4; ++k) {
                    const unsigned long long u = d[4 + k];
                    s1[tid + 512 * k] = make_float2(
                        __uint_as_float((unsigned)u & PAYMASK),
                        __uint_as_float((unsigned)(u >> 32) & PAYMASK));
                }
            }
        }
        __syncthreads();   // the ONE barrier per round

        // ---- fused FMA: v0 = Whh0 h0; v1 = Wih1 h0 + Whh1 h1 ----
        float v0[16] = {}, v1[16] = {};
#pragma unroll
        for (int q = 0; q < 16; ++q) {
            const float2 a0 = s0[q * 64 + kg];          // h0, batches 0,1
            const float2 a1 = s0[1024 + q * 64 + kg];   // h0, batches 2,3
            const float2 c0 = s1[q * 64 + kg];          // h1, batches 0,1
            const float2 c1 = s1[1024 + q * 64 + kg];   // h1, batches 2,3
#pragma unroll
            for (int i = 0; i < 4; ++i) {
                const float fa = w0[i][q];
                v0[i*4+0] += fa * a0.x; v0[i*4+1] += fa * a0.y;
                v0[i*4+2] += fa * a1.x; v0[i*4+3] += fa * a1.y;
                const float fb = wx[i][q];
                v1[i*4+0] += fb * a0.x; v1[i*4+1] += fb * a0.y;
                v1[i*4+2] += fb * a1.x; v1[i*4+3] += fb * a1.y;
                const float fc = wh[i][q];
                v1[i*4+0] += fc * c0.x; v1[i*4+1] += fc * c0.y;
                v1[i*4+2] += fc * c1.x; v1[i*4+3] += fc * c1.y;
            }
        }

        // ---- tree(v0): lane p -> out(p&15), a = i*4+b ----
#pragma unroll
        for (int st = 0; st < 4; ++st) {
            const int m  = 1 << st;
            const int nh = 8 >> st;
            const bool hi = (kg & m) != 0;
#pragma unroll
            for (int j = 0; j < 8; ++j) {
                if (j < nh) {
                    const float a0 = v0[2*j], a1 = v0[2*j+1];
                    const float got = __shfl_xor(hi ? a0 : a1, m, 64);
                    v0[j] = (hi ? a1 : a0) + got;
                }
            }
        }
        v0[0] += __shfl_xor(v0[0], 16, 64);
        v0[0] += __shfl_xor(v0[0], 32, 64);

        // ---- publish h0(r) early (consumers can detect during v1 work) ----
        if (r < S_) {
            float h0 = 0.f;
            if (kg < 16) h0 = tanhf(xpv + v0[0]);
            const float h0p = __shfl_xor(h0, 1, 64);   // partner batch
            if (kg < 16 && (bb & 1) == 0) {
                const unsigned eb = (((unsigned)r >> 2) & 1u) << 30;
                const unsigned long long u =
                    ((unsigned long long)(__float_as_uint(h0p) | eb) << 32) |
                    (unsigned long long)(__float_as_uint(h0) | eb);
                astore64(exg + (size_t)(r & 3) * LS_STRIDE
                             + ((size_t)(bb >> 1) << 10) + ok, u);
            }
        }

        // ---- tree(v1) ----
#pragma unroll
        for (int st = 0; st < 4; ++st) {
            const int m  = 1 << st;
            const int nh = 8 >> st;
            const bool hi = (kg & m) != 0;
#pragma unroll
            for (int j = 0; j < 8; ++j) {
                if (j < nh) {
                    const float a0 = v1[2*j], a1 = v1[2*j+1];
                    const float got = __shfl_xor(hi ? a0 : a1, m, 64);
                    v1[j] = (hi ? a1 : a0) + got;
                }
            }
        }
        v1[0] += __shfl_xor(v1[0], 16, 64);
        v1[0] += __shfl_xor(v1[0], 32, 64);

        // ---- h1(r-1): global write (for logits GEMM) + publish ----
        if (r >= 1) {
            float h1 = 0.f;
            if (kg < 16) h1 = tanhf(v1[0] + bsum);
            const float h1p = __shfl_xor(h1, 1, 64);
            if (kg < 16) *px1 = h1;     // overwrites consumed xp0 (b, r-1, ok)
            if (kg < 16 && (bb & 1) == 0) {
                const unsigned eb = (((unsigned)r >> 2) & 1u) << 30;
                const unsigned long long u =
                    ((unsigned long long)(__float_as_uint(h1p) | eb) << 32) |
                    (unsigned long long)(__float_as_uint(h1) | eb);
                astore64(exg + (size_t)(4 + (r & 3)) * LS_STRIDE
                             + ((size_t)(bb >> 1) << 10) + ok, u);
            }
            px1 += HID_;
        }
        // no trailing barrier: double-buffered planes (see header)
    }
}

extern "C" void kernel_launch(void* const* d_in, const int* in_sizes, int n_in,
                              void* d_out, int out_size, void* d_ws, size_t ws_size,
                              hipStream_t stream)
{
    const int*   tokens = (const int*)  d_in[0];
    const float* emb    = (const float*)d_in[1];
    const float* W_ih0  = (const float*)d_in[2];
    const float* W_hh0  = (const float*)d_in[3];
    const float* b_ih0  = (const float*)d_in[4];
    const float* b_hh0  = (const float*)d_in[5];
    const float* W_ih1  = (const float*)d_in[6];
    const float* W_hh1  = (const float*)d_in[7];
    const float* b_ih1  = (const float*)d_in[8];
    const float* b_hh1  = (const float*)d_in[9];
    const float* W_out  = (const float*)d_in[10];
    const float* b_out  = (const float*)d_in[11];
    float* out = (float*)d_out;

    float* buf = (float*)d_ws;                            // 64 MiB: xp0 -> h1
    unsigned long long* ex = (unsigned long long*)d_out;  // 1 MB exchange

    // 96 KB dynamic LDS -> exactly 1 WG/CU (256 WGs co-resident on 256 CUs)
    const size_t scan_lds = 98304;
    hipFuncSetAttribute((const void*)rnn_fused,
                        hipFuncAttributeMaxDynamicSharedMemorySize, (int)scan_lds);

    // 1) xp0 = gather(emb,tokens) @ W_ih0^T + b_ih0 + b_hh0  -> buf
    gemm_bias<<<dim3(HID_ / 64, M_ / 128), 256, 0, stream>>>(
        emb, tokens, W_ih0, b_ih0, b_hh0, buf, M_, EMB_, HID_);

    // 2) pre-fill exchange epochs
    fill_poison<<<EX_TOTAL / 256, 256, 0, stream>>>(ex, EX_TOTAL);

    // 3) fused 2-layer skewed scan: xp0 consumed, h1 left in buf
    rnn_fused<<<256, 512, scan_lds, stream>>>(
        W_hh0, W_hh1, W_ih1, b_ih1, b_hh1, buf, ex);

    // 4) out = h1 @ W_out^T + b_out (fully rewrites d_out incl. ex region)
    gemm_bias<<<dim3(LAB_ / 64, M_ / 128), 256, 0, stream>>>(
        buf, nullptr, W_out, b_out, nullptr, out, M_, HID_, LAB_);
}

// Round 7
// 3675.391 us; speedup vs baseline: 3.2739x; 3.2739x over previous
//
#include <hip/hip_runtime.h>
#include <math.h>

#define B_    32
#define S_    512
#define EMB_  512
#define HID_  1024
#define LAB_  64
#define M_    (B_ * S_)

// ---------------------------------------------------------------------------
// R16: FUSED two-layer skewed pipeline (R15 structure), DE-SPILLED.
// R15 post-mortem: 192 weight regs + 32 accs + d[8] staging + addressing
// ~= 280 > 256-reg cap (8 waves/CU) -> scratch spill in the round loop ->
// FETCH 15.5 GB, 11.7 ms. R16 cuts ~48 regs of demand: stage-on-accept
// (no d[8]) + two-pass accumulation (16 accs live, not 32). No structural
// change to the pipeline or the exchange protocol.
//
// Pipeline (round r = 0..512), 256 WGs x 512 thr, 1 WG/CU:
//   layer-0 step r   (r<512): h0(r) = tanh(xp0(r) + Whh0 h0(r-1))
//   layer-1 step r-1 (r>=1):  h1(r-1) = tanh(Wih1 h0(r-1) + Whh1 h1(r-2) + b)
// Both consumed vectors were published at round r-1 -> uniform 1-round
// skew, ONE poll phase + ONE barrier per round; 513 serial handshakes
// (vs 1024) and no xp1 GEMM. h1 overwrites consumed xp0 in place.
//
// Exchange (epoch-bit protocol, two regions, depth-4 slots):
//   word = u64 {enc(h[2c]) lo, enc(h[2c+1]) hi}, enc = bits|((r>>2)&1)<<30
//   (tanh => bit30 always 0). ex[(L*4+slot)*16384 + g*2048 + c*1024 + n],
//   131072 u64 = 1 MB in d_out. Publish r -> slot r&3; consume r -> slot
//   (r-1)&3, epoch ((r-1)>>2)&1. Skew<=1 => only stale content possible is
//   4 rounds old = opposite epoch. Startup: every address's first poll
//   expects epoch 0 except L1 slot 0 (first polled round 5, epoch 1;
//   first published round 4) -> fill L1 slot 0 epoch-0-looking, the rest
//   epoch-1-looking.
// ---------------------------------------------------------------------------
#define SLOT_U64   2048                   // per (layer,slot,group)
#define LS_STRIDE  (8 * SLOT_U64)         // per (layer,slot)
#define EX_TOTAL   (2 * 4 * LS_STRIDE)    // 131072 u64 = 1 MB
#define EPMASK64   0x4000000040000000ULL
#define NANPAT64   0x7FC000007FC00000ULL  // epoch-1-looking fill
#define ONEPAT64   0x3F8000003F800000ULL  // epoch-0-looking fill (L1 slot 0)
#define PAYMASK    0xBFFFFFFFu

__device__ __forceinline__ unsigned long long aload64(const unsigned long long* p) {
    return __hip_atomic_load((unsigned long long*)p, __ATOMIC_RELAXED,
                             __HIP_MEMORY_SCOPE_AGENT);
}
__device__ __forceinline__ void astore64(unsigned long long* p, unsigned long long v) {
    __hip_atomic_store(p, v, __ATOMIC_RELAXED, __HIP_MEMORY_SCOPE_AGENT);
}
__device__ __forceinline__ float2 exdec(unsigned long long u) {
    return make_float2(__uint_as_float((unsigned)u & PAYMASK),
                       __uint_as_float((unsigned)(u >> 32) & PAYMASK));
}
// 16-acc halving-tree: after masks 1,2,4,8 + 16,32, lane p holds out(p&15).
__device__ __forceinline__ float fold16(float* v, int kg) {
#pragma unroll
    for (int st = 0; st < 4; ++st) {
        const int m  = 1 << st;
        const int nh = 8 >> st;
        const bool hi = (kg & m) != 0;
#pragma unroll
        for (int j = 0; j < 8; ++j) {
            if (j < nh) {
                const float a0 = v[2*j], a1 = v[2*j+1];
                const float got = __shfl_xor(hi ? a0 : a1, m, 64);
                v[j] = (hi ? a1 : a0) + got;
            }
        }
    }
    float r = v[0];
    r += __shfl_xor(r, 16, 64);
    r += __shfl_xor(r, 32, 64);
    return r;
}

// ---------------------------------------------------------------------------
// fp32 tiled GEMM (unchanged): BM=128, BN=64, BK=16, 256 thr, 8x4/thread.
// ---------------------------------------------------------------------------
__global__ __launch_bounds__(256) void gemm_bias(
    const float* __restrict__ A, const int* __restrict__ tokens,
    const float* __restrict__ W, const float* __restrict__ bias,
    const float* __restrict__ bias2, float* __restrict__ C,
    int M, int K, int N)
{
    __shared__ float As[128][17];
    __shared__ float Ws[64][17];

    const int tid = threadIdx.x;
    const int tx  = tid & 15;
    const int ty  = tid >> 4;
    const int n0  = blockIdx.x * 64;
    const int m0  = blockIdx.y * 128;

    const int lr  = tid >> 2;
    const int lk  = (tid & 3) << 2;

    const int ar0 = tokens ? tokens[m0 + lr]      : (m0 + lr);
    const int ar1 = tokens ? tokens[m0 + 64 + lr] : (m0 + 64 + lr);
    const float* __restrict__ arow0 = A + (size_t)ar0 * K;
    const float* __restrict__ arow1 = A + (size_t)ar1 * K;
    const float* __restrict__ wrow  = W + (size_t)(n0 + lr) * K;

    float bs[4];
#pragma unroll
    for (int j = 0; j < 4; ++j) {
        int n = n0 + tx * 4 + j;
        bs[j] = bias[n] + (bias2 ? bias2[n] : 0.0f);
    }

    float acc[8][4] = {};

    for (int k0 = 0; k0 < K; k0 += 16) {
        const float4 a0 = *(const float4*)(arow0 + k0 + lk);
        const float4 a1 = *(const float4*)(arow1 + k0 + lk);
        const float4 wv = *(const float4*)(wrow  + k0 + lk);
        __syncthreads();
        As[lr][lk + 0] = a0.x; As[lr][lk + 1] = a0.y;
        As[lr][lk + 2] = a0.z; As[lr][lk + 3] = a0.w;
        As[64 + lr][lk + 0] = a1.x; As[64 + lr][lk + 1] = a1.y;
        As[64 + lr][lk + 2] = a1.z; As[64 + lr][lk + 3] = a1.w;
        Ws[lr][lk + 0] = wv.x; Ws[lr][lk + 1] = wv.y;
        Ws[lr][lk + 2] = wv.z; Ws[lr][lk + 3] = wv.w;
        __syncthreads();

#pragma unroll
        for (int kk = 0; kk < 16; ++kk) {
            float b[4], a[8];
#pragma unroll
            for (int j = 0; j < 4; ++j) b[j] = Ws[tx * 4 + j][kk];
#pragma unroll
            for (int i = 0; i < 8; ++i) a[i] = As[ty * 8 + i][kk];
#pragma unroll
            for (int i = 0; i < 8; ++i)
#pragma unroll
                for (int j = 0; j < 4; ++j)
                    acc[i][j] += a[i] * b[j];
        }
    }

#pragma unroll
    for (int i = 0; i < 8; ++i) {
        const int m = m0 + ty * 8 + i;
        float4 v;
        v.x = acc[i][0] + bs[0];
        v.y = acc[i][1] + bs[1];
        v.z = acc[i][2] + bs[2];
        v.w = acc[i][3] + bs[3];
        *(float4*)(C + (size_t)m * N + n0 + tx * 4) = v;
    }
}

// ---------------------------------------------------------------------------
// Fill: NANPAT (epoch-1-look) everywhere except L1 slot 0 (ls index 4).
// ---------------------------------------------------------------------------
__global__ __launch_bounds__(256) void fill_poison(unsigned long long* p, int n)
{
    const int i = blockIdx.x * 256 + threadIdx.x;
    if (i < n) {
        const int ls = i / LS_STRIDE;          // layer*4 + slot
        p[i] = (ls == 4) ? ONEPAT64 : NANPAT64;
    }
}

// ---------------------------------------------------------------------------
// Fused 2-layer skewed scan, de-spilled. Weights: 3 x (4n x 16q) = 192
// regs. Peak live: 192 + 16 accs + temps ~= 238 < 256 (8 waves/CU cap).
// LDS: 4 planes (h0/h1 x dbuf) x 2048 float2 = 64 KB. One barrier/round;
// dbuf safety: reads of plane[r&1] (post-barrier r) precede this thread's
// barrier(r+1); overwrites of plane[r&1] (staging r+2) follow barrier(r+1).
// ---------------------------------------------------------------------------
__global__ __launch_bounds__(512, 2) void rnn_fused(
    const float* __restrict__ Whh0, const float* __restrict__ Whh1,
    const float* __restrict__ Wih1, const float* __restrict__ b_ih1,
    const float* __restrict__ b_hh1, float* __restrict__ xb,
    unsigned long long* __restrict__ ex)
{
    extern __shared__ float smem[];
    float2* hb = (float2*)smem;        // [2 layer][2 buf][2048] float2

    const int wg  = blockIdx.x;
    const int g   = wg & 7;            // group: batches g*4..g*4+3
    const int s   = wg >> 3;           // slice: neurons s*32..s*32+31
    const int tid = threadIdx.x;       // 0..511
    const int j8  = tid >> 6;          // wave: neurons s*32 + j8*4 ..+3
    const int kg  = tid & 63;          // lane; k = kg + 64q
    const int b0  = g * 4;

    // weights: 4 neurons x 16 strided k, three matrices (lane-coalesced)
    float w0[4][16], wx[4][16], wh[4][16];
    {
        const size_t base = (size_t)(s * 32 + j8 * 4) * HID_ + kg;
#pragma unroll
        for (int i = 0; i < 4; ++i)
#pragma unroll
            for (int q = 0; q < 16; ++q) {
                const size_t o = base + (size_t)i * HID_ + (size_t)q * 64;
                w0[i][q] = Whh0[o];
                wx[i][q] = Wih1[o];
                wh[i][q] = Whh1[o];
            }
    }

    const int i4 = (kg >> 2) & 3;      // output neuron (lanes<16)
    const int bb = kg & 3;             // output batch  (lanes<16)
    const int ok = s * 32 + j8 * 4 + i4;
    float bsum = 0.f;
    if (kg < 16) bsum = b_ih1[ok] + b_hh1[ok];

    float* px0 = xb + ((size_t)(b0 + bb) * S_) * HID_ + ok;  // xp0 read (b,r)
    float* px1 = px0;                                        // h1 write (b,r-1)

    unsigned long long* const exg = ex + (size_t)g * SLOT_U64;

    for (int r = 0; r <= S_; ++r) {
        // ---- xp0 prefetch (overlaps the poll) ----
        float xpv = 0.f;
        if (kg < 16 && r < S_) xpv = *px0;
        px0 += HID_;

        const int cur = r & 1;
        float2* s0 = hb + (size_t)cur * 2048;          // h0(r-1) plane
        float2* s1 = hb + (size_t)(2 + cur) * 2048;    // h1(r-2) plane

        // ---- stage: poll slot (r-1)&3 of both regions, stage-on-accept ----
        if (r == 0) {
#pragma unroll
            for (int k = 0; k < 4; ++k) {
                s0[tid + 512 * k] = make_float2(0.f, 0.f);
                s1[tid + 512 * k] = make_float2(0.f, 0.f);
            }
        } else {
            const int sl = (r - 1) & 3;
            const unsigned long long want =
                (((unsigned)(r - 1) >> 2) & 1u) ? EPMASK64 : 0ULL;
            const unsigned long long* pl0 = exg + (size_t)sl * LS_STRIDE;
            const unsigned long long* pl1 = exg + (size_t)(4 + sl) * LS_STRIDE;
            unsigned pend = (r >= 2) ? 0xFFu : 0x0Fu;
            if (r == 1) {
#pragma unroll
                for (int k = 0; k < 4; ++k)
                    s1[tid + 512 * k] = make_float2(0.f, 0.f);
            }
            do {
#pragma unroll
                for (int k = 0; k < 4; ++k) {
                    if (pend & (1u << k)) {
                        const unsigned long long u = aload64(pl0 + tid + 512 * k);
                        if ((u & EPMASK64) == want) {
                            s0[tid + 512 * k] = exdec(u);
                            pend &= ~(1u << k);
                        }
                    }
                    if (pend & (1u << (4 + k))) {
                        const unsigned long long u = aload64(pl1 + tid + 512 * k);
                        if ((u & EPMASK64) == want) {
                            s1[tid + 512 * k] = exdec(u);
                            pend &= ~(1u << (4 + k));
                        }
                    }
                }
            } while (pend);
        }
        __syncthreads();   // the ONE barrier per round

        // ---- pass A: v = Whh0 h0(r-1); fold; publish h0(r) early ----
        {
            float v[16] = {};
#pragma unroll
            for (int q = 0; q < 16; ++q) {
                const float2 a0 = s0[q * 64 + kg];          // h0, batches 0,1
                const float2 a1 = s0[1024 + q * 64 + kg];   // h0, batches 2,3
#pragma unroll
                for (int i = 0; i < 4; ++i) {
                    const float fa = w0[i][q];
                    v[i*4+0] += fa * a0.x; v[i*4+1] += fa * a0.y;
                    v[i*4+2] += fa * a1.x; v[i*4+3] += fa * a1.y;
                }
            }
            const float r0 = fold16(v, kg);
            if (r < S_) {
                float h0 = 0.f;
                if (kg < 16) h0 = tanhf(xpv + r0);
                const float h0p = __shfl_xor(h0, 1, 64);   // partner batch
                if (kg < 16 && (bb & 1) == 0) {
                    const unsigned eb = (((unsigned)r >> 2) & 1u) << 30;
                    const unsigned long long u =
                        ((unsigned long long)(__float_as_uint(h0p) | eb) << 32) |
                        (unsigned long long)(__float_as_uint(h0) | eb);
                    astore64(exg + (size_t)(r & 3) * LS_STRIDE
                                 + ((size_t)(bb >> 1) << 10) + ok, u);
                }
            }
        }

        // ---- pass B: v = Wih1 h0(r-1) + Whh1 h1(r-2); fold; h1(r-1) ----
        if (r >= 1) {
            float v[16] = {};
#pragma unroll
            for (int q = 0; q < 16; ++q) {
                const float2 a0 = s0[q * 64 + kg];
                const float2 a1 = s0[1024 + q * 64 + kg];
                const float2 c0 = s1[q * 64 + kg];
                const float2 c1 = s1[1024 + q * 64 + kg];
#pragma unroll
                for (int i = 0; i < 4; ++i) {
                    const float fb = wx[i][q];
                    v[i*4+0] += fb * a0.x; v[i*4+1] += fb * a0.y;
                    v[i*4+2] += fb * a1.x; v[i*4+3] += fb * a1.y;
                    const float fc = wh[i][q];
                    v[i*4+0] += fc * c0.x; v[i*4+1] += fc * c0.y;
                    v[i*4+2] += fc * c1.x; v[i*4+3] += fc * c1.y;
                }
            }
            const float r1 = fold16(v, kg);
            float h1 = 0.f;
            if (kg < 16) h1 = tanhf(r1 + bsum);
            const float h1p = __shfl_xor(h1, 1, 64);
            if (kg < 16) *px1 = h1;     // overwrites consumed xp0 (b, r-1, ok)
            if (kg < 16 && (bb & 1) == 0) {
                const unsigned eb = (((unsigned)r >> 2) & 1u) << 30;
                const unsigned long long u =
                    ((unsigned long long)(__float_as_uint(h1p) | eb) << 32) |
                    (unsigned long long)(__float_as_uint(h1) | eb);
                astore64(exg + (size_t)(4 + (r & 3)) * LS_STRIDE
                             + ((size_t)(bb >> 1) << 10) + ok, u);
            }
            px1 += HID_;
        }
        // no trailing barrier: double-buffered planes (see header)
    }
}

extern "C" void kernel_launch(void* const* d_in, const int* in_sizes, int n_in,
                              void* d_out, int out_size, void* d_ws, size_t ws_size,
                              hipStream_t stream)
{
    const int*   tokens = (const int*)  d_in[0];
    const float* emb    = (const float*)d_in[1];
    const float* W_ih0  = (const float*)d_in[2];
    const float* W_hh0  = (const float*)d_in[3];
    const float* b_ih0  = (const float*)d_in[4];
    const float* b_hh0  = (const float*)d_in[5];
    const float* W_ih1  = (const float*)d_in[6];
    const float* W_hh1  = (const float*)d_in[7];
    const float* b_ih1  = (const float*)d_in[8];
    const float* b_hh1  = (const float*)d_in[9];
    const float* W_out  = (const float*)d_in[10];
    const float* b_out  = (const float*)d_in[11];
    float* out = (float*)d_out;

    float* buf = (float*)d_ws;                            // 64 MiB: xp0 -> h1
    unsigned long long* ex = (unsigned long long*)d_out;  // 1 MB exchange

    // 96 KB dynamic LDS -> exactly 1 WG/CU (256 WGs co-resident on 256 CUs)
    const size_t scan_lds = 98304;
    hipFuncSetAttribute((const void*)rnn_fused,
                        hipFuncAttributeMaxDynamicSharedMemorySize, (int)scan_lds);

    // 1) xp0 = gather(emb,tokens) @ W_ih0^T + b_ih0 + b_hh0  -> buf
    gemm_bias<<<dim3(HID_ / 64, M_ / 128), 256, 0, stream>>>(
        emb, tokens, W_ih0, b_ih0, b_hh0, buf, M_, EMB_, HID_);

    // 2) pre-fill exchange epochs
    fill_poison<<<EX_TOTAL / 256, 256, 0, stream>>>(ex, EX_TOTAL);

    // 3) fused 2-layer skewed scan: xp0 consumed, h1 left in buf
    rnn_fused<<<256, 512, scan_lds, stream>>>(
        W_hh0, W_hh1, W_ih1, b_ih1, b_hh1, buf, ex);

    // 4) out = h1 @ W_out^T + b_out (fully rewrites d_out incl. ex region)
    gemm_bias<<<dim3(LAB_ / 64, M_ / 128), 256, 0, stream>>>(
        buf, nullptr, W_out, b_out, nullptr, out, M_, HID_, LAB_);
}

// Round 8
// 3257.957 us; speedup vs baseline: 3.6934x; 1.1281x over previous
//
#include <hip/hip_runtime.h>
#include <math.h>

#define B_    32
#define S_    512
#define EMB_  512
#define HID_  1024
#define LAB_  64
#define M_    (B_ * S_)

// ---------------------------------------------------------------------------
// R17: fused two-layer skewed pipeline (R16) + 16B coalesced polls + split
// barriers. R16 post-mortem: 4096 polled words/WG/round (4x R14) re-created
// the poll-congestion collapse (~4.7k cyc/SIMD/round of spin VALU). R17:
//  (1) word layout [layer,slot,group]: idx = neuron*2 + chunk  -> a thread
//      polls 2 contiguous u64 per load = global_load_dwordx4 sc1 (agent
//      scope, same flags the builtin emits), lane-stride 16B = coalesced.
//      Requests/sweep halved.
//  (2) two barriers/round: stage h0 | barrier | passA + publish h0 |
//      poll+stage h1 | barrier | passB + publish h1. Staggers the two poll
//      phases and gives the end-of-round h1 publish a passA-length grace.
//  (3) stores unchanged (astore64; not the bottleneck).
//
// Pipeline (round r = 0..512), 256 WGs x 512 thr, 1 WG/CU:
//   layer-0 step r   (r<512): h0(r) = tanh(xp0(r) + Whh0 h0(r-1))
//   layer-1 step r-1 (r>=1):  h1(r-1) = tanh(Wih1 h0(r-1) + Whh1 h1(r-2) + b)
// h1 overwrites consumed xp0 in place; no xp1 GEMM.
//
// Exchange (epoch-bit protocol, depth-4 slots):
//   word = u64 {enc(h[b0,n]) lo, enc(h[b1,n]) hi}, enc = bits|((r>>2)&1)<<30
//   (tanh => bit30 of fp32 always 0). Publish r -> slot r&3; consume r ->
//   slot (r-1)&3, epoch ((r-1)>>2)&1. Skew<=1 (staging r requires ALL
//   publishes r-1) => only possible stale slot content is 4 rounds old =
//   opposite epoch. Startup fill: every address's first poll expects epoch 0
//   except L1 slot 0 (first polled round 5 with epoch 1) -> fill L1 slot 0
//   epoch-0-looking (ONEPAT), the rest epoch-1-looking (NANPAT).
// LDS dbuf safety (2 barriers): reads of a plane (post-barrier-k of round r)
// precede this thread's next barrier, which (WG-wide) precedes any staging
// overwrite of that plane at round r+2.
// ---------------------------------------------------------------------------
#define SLOT_U64   2048                   // per (layer,slot,group)
#define LS_STRIDE  (8 * SLOT_U64)         // per (layer,slot)
#define EX_TOTAL   (2 * 4 * LS_STRIDE)    // 131072 u64 = 1 MB
#define EPBIT      0x40000000u
#define NANPAT64   0x7FC000007FC00000ULL  // epoch-1-looking fill
#define ONEPAT64   0x3F8000003F800000ULL  // epoch-0-looking fill (L1 slot 0)
#define PAYMASK    0xBFFFFFFFu

typedef unsigned int u32x4 __attribute__((ext_vector_type(4)));

__device__ __forceinline__ void astore64(unsigned long long* p, unsigned long long v) {
    __hip_atomic_store(p, v, __ATOMIC_RELAXED, __HIP_MEMORY_SCOPE_AGENT);
}
// two 16B agent-scope polls in one issue window (one RT per sweep)
__device__ __forceinline__ void apoll2(const unsigned long long* q0,
                                       const unsigned long long* q1,
                                       u32x4& w0, u32x4& w1) {
    asm volatile(
        "global_load_dwordx4 %0, %2, off sc1\n\t"
        "global_load_dwordx4 %1, %3, off sc1\n\t"
        "s_waitcnt vmcnt(0)"
        : "=&v"(w0), "=&v"(w1)
        : "v"(q0), "v"(q1)
        : "memory");
}
__device__ __forceinline__ bool epok4(u32x4 v, unsigned eb) {
    return ((((v[0] ^ eb) | (v[1] ^ eb)) | ((v[2] ^ eb) | (v[3] ^ eb)))
            & EPBIT) == 0;
}
// 16-acc halving-tree: after masks 1,2,4,8 + 16,32, lane p holds out(p&15).
__device__ __forceinline__ float fold16(float* v, int kg) {
#pragma unroll
    for (int st = 0; st < 4; ++st) {
        const int m  = 1 << st;
        const int nh = 8 >> st;
        const bool hi = (kg & m) != 0;
#pragma unroll
        for (int j = 0; j < 8; ++j) {
            if (j < nh) {
                const float a0 = v[2*j], a1 = v[2*j+1];
                const float got = __shfl_xor(hi ? a0 : a1, m, 64);
                v[j] = (hi ? a1 : a0) + got;
            }
        }
    }
    float r = v[0];
    r += __shfl_xor(r, 16, 64);
    r += __shfl_xor(r, 32, 64);
    return r;
}

// ---------------------------------------------------------------------------
// fp32 tiled GEMM (unchanged): BM=128, BN=64, BK=16, 256 thr, 8x4/thread.
// ---------------------------------------------------------------------------
__global__ __launch_bounds__(256) void gemm_bias(
    const float* __restrict__ A, const int* __restrict__ tokens,
    const float* __restrict__ W, const float* __restrict__ bias,
    const float* __restrict__ bias2, float* __restrict__ C,
    int M, int K, int N)
{
    __shared__ float As[128][17];
    __shared__ float Ws[64][17];

    const int tid = threadIdx.x;
    const int tx  = tid & 15;
    const int ty  = tid >> 4;
    const int n0  = blockIdx.x * 64;
    const int m0  = blockIdx.y * 128;

    const int lr  = tid >> 2;
    const int lk  = (tid & 3) << 2;

    const int ar0 = tokens ? tokens[m0 + lr]      : (m0 + lr);
    const int ar1 = tokens ? tokens[m0 + 64 + lr] : (m0 + 64 + lr);
    const float* __restrict__ arow0 = A + (size_t)ar0 * K;
    const float* __restrict__ arow1 = A + (size_t)ar1 * K;
    const float* __restrict__ wrow  = W + (size_t)(n0 + lr) * K;

    float bs[4];
#pragma unroll
    for (int j = 0; j < 4; ++j) {
        int n = n0 + tx * 4 + j;
        bs[j] = bias[n] + (bias2 ? bias2[n] : 0.0f);
    }

    float acc[8][4] = {};

    for (int k0 = 0; k0 < K; k0 += 16) {
        const float4 a0 = *(const float4*)(arow0 + k0 + lk);
        const float4 a1 = *(const float4*)(arow1 + k0 + lk);
        const float4 wv = *(const float4*)(wrow  + k0 + lk);
        __syncthreads();
        As[lr][lk + 0] = a0.x; As[lr][lk + 1] = a0.y;
        As[lr][lk + 2] = a0.z; As[lr][lk + 3] = a0.w;
        As[64 + lr][lk + 0] = a1.x; As[64 + lr][lk + 1] = a1.y;
        As[64 + lr][lk + 2] = a1.z; As[64 + lr][lk + 3] = a1.w;
        Ws[lr][lk + 0] = wv.x; Ws[lr][lk + 1] = wv.y;
        Ws[lr][lk + 2] = wv.z; Ws[lr][lk + 3] = wv.w;
        __syncthreads();

#pragma unroll
        for (int kk = 0; kk < 16; ++kk) {
            float b[4], a[8];
#pragma unroll
            for (int j = 0; j < 4; ++j) b[j] = Ws[tx * 4 + j][kk];
#pragma unroll
            for (int i = 0; i < 8; ++i) a[i] = As[ty * 8 + i][kk];
#pragma unroll
            for (int i = 0; i < 8; ++i)
#pragma unroll
                for (int j = 0; j < 4; ++j)
                    acc[i][j] += a[i] * b[j];
        }
    }

#pragma unroll
    for (int i = 0; i < 8; ++i) {
        const int m = m0 + ty * 8 + i;
        float4 v;
        v.x = acc[i][0] + bs[0];
        v.y = acc[i][1] + bs[1];
        v.z = acc[i][2] + bs[2];
        v.w = acc[i][3] + bs[3];
        *(float4*)(C + (size_t)m * N + n0 + tx * 4) = v;
    }
}

// ---------------------------------------------------------------------------
// Fill: NANPAT (epoch-1-look) everywhere except L1 slot 0 (ls index 4).
// ---------------------------------------------------------------------------
__global__ __launch_bounds__(256) void fill_poison(unsigned long long* p, int n)
{
    const int i = blockIdx.x * 256 + threadIdx.x;
    if (i < n) {
        const int ls = i / LS_STRIDE;          // layer*4 + slot
        p[i] = (ls == 4) ? ONEPAT64 : NANPAT64;
    }
}

// ---------------------------------------------------------------------------
// Fused 2-layer skewed scan. Weights: 3 x (4n x 16q) = 192 regs/thread.
// LDS: 4 planes (h0/h1 x dbuf) x 2048 float2 = 64 KB. Two barriers/round.
// Partition: slice s = wg>>3 (32 neurons), group g = wg&7 (4 batches).
// ---------------------------------------------------------------------------
__global__ __launch_bounds__(512, 2) void rnn_fused(
    const float* __restrict__ Whh0, const float* __restrict__ Whh1,
    const float* __restrict__ Wih1, const float* __restrict__ b_ih1,
    const float* __restrict__ b_hh1, float* __restrict__ xb,
    unsigned long long* __restrict__ ex)
{
    extern __shared__ float smem[];
    float2* hb = (float2*)smem;        // [2 layer][2 buf][2048] float2

    const int wg  = blockIdx.x;
    const int g   = wg & 7;            // group: batches g*4..g*4+3
    const int s   = wg >> 3;           // slice: neurons s*32..s*32+31
    const int tid = threadIdx.x;       // 0..511
    const int j8  = tid >> 6;          // wave: neurons s*32 + j8*4 ..+3
    const int kg  = tid & 63;          // lane; k = kg + 64q
    const int b0  = g * 4;

    // weights: 4 neurons x 16 strided k, three matrices (lane-coalesced)
    float w0[4][16], wx[4][16], wh[4][16];
    {
        const size_t base = (size_t)(s * 32 + j8 * 4) * HID_ + kg;
#pragma unroll
        for (int i = 0; i < 4; ++i)
#pragma unroll
            for (int q = 0; q < 16; ++q) {
                const size_t o = base + (size_t)i * HID_ + (size_t)q * 64;
                w0[i][q] = Whh0[o];
                wx[i][q] = Wih1[o];
                wh[i][q] = Whh1[o];
            }
    }

    const int i4 = (kg >> 2) & 3;      // output neuron (lanes<16)
    const int bb = kg & 3;             // output batch  (lanes<16)
    const int ok = s * 32 + j8 * 4 + i4;
    float bsum = 0.f;
    if (kg < 16) bsum = b_ih1[ok] + b_hh1[ok];

    float* px0 = xb + ((size_t)(b0 + bb) * S_) * HID_ + ok;  // xp0 read (b,r)
    float* px1 = px0;                                        // h1 write (b,r-1)

    unsigned long long* const exg = ex + (size_t)g * SLOT_U64;
    // consumer 16B lines: neurons tid and 512+tid (words 2n, 2n+1)
    const int c0 = 2 * tid, c1 = 1024 + 2 * tid;

    for (int r = 0; r <= S_; ++r) {
        // ---- xp0 prefetch (overlaps the h0 poll) ----
        float xpv = 0.f;
        if (kg < 16 && r < S_) xpv = *px0;
        px0 += HID_;

        const int cur = r & 1;
        float2* s0 = hb + (size_t)cur * 2048;          // h0(r-1) plane
        float2* s1 = hb + (size_t)(2 + cur) * 2048;    // h1(r-2) plane

        const int sl = (r - 1) & 3;
        const unsigned eb = ((((unsigned)(r - 1)) >> 2) & 1u) << 30;

        // ---- phase 1: stage h0(r-1) ----
        if (r == 0) {
#pragma unroll
            for (int k = 0; k < 4; ++k)
                s0[tid + 512 * k] = make_float2(0.f, 0.f);
        } else {
            const unsigned long long* pl = exg + (size_t)sl * LS_STRIDE;
            unsigned pend = 3u;
            u32x4 w0v, w1v;
            do {
                apoll2(pl + c0, pl + c1, w0v, w1v);
                if ((pend & 1u) && epok4(w0v, eb)) {
                    s0[tid]        = make_float2(
                        __uint_as_float(w0v[0] & PAYMASK),
                        __uint_as_float(w0v[1] & PAYMASK));
                    s0[1024 + tid] = make_float2(
                        __uint_as_float(w0v[2] & PAYMASK),
                        __uint_as_float(w0v[3] & PAYMASK));
                    pend &= ~1u;
                }
                if ((pend & 2u) && epok4(w1v, eb)) {
                    s0[512 + tid]  = make_float2(
                        __uint_as_float(w1v[0] & PAYMASK),
                        __uint_as_float(w1v[1] & PAYMASK));
                    s0[1536 + tid] = make_float2(
                        __uint_as_float(w1v[2] & PAYMASK),
                        __uint_as_float(w1v[3] & PAYMASK));
                    pend &= ~2u;
                }
            } while (pend);
        }
        __syncthreads();   // barrier 1: h0 staged -> passA may read

        // ---- pass A: v = Whh0 h0(r-1); fold; publish h0(r) ----
        {
            float v[16] = {};
#pragma unroll
            for (int q = 0; q < 16; ++q) {
                const float2 a0 = s0[q * 64 + kg];          // batches 0,1
                const float2 a1 = s0[1024 + q * 64 + kg];   // batches 2,3
#pragma unroll
                for (int i = 0; i < 4; ++i) {
                    const float fa = w0[i][q];
                    v[i*4+0] += fa * a0.x; v[i*4+1] += fa * a0.y;
                    v[i*4+2] += fa * a1.x; v[i*4+3] += fa * a1.y;
                }
            }
            const float r0 = fold16(v, kg);
            if (r < S_) {
                float h0 = 0.f;
                if (kg < 16) h0 = tanhf(xpv + r0);
                const float h0p = __shfl_xor(h0, 1, 64);   // partner batch
                if (kg < 16 && (bb & 1) == 0) {
                    const unsigned pe = (((unsigned)r >> 2) & 1u) << 30;
                    const unsigned long long u =
                        ((unsigned long long)(__float_as_uint(h0p) | pe) << 32) |
                        (unsigned long long)(__float_as_uint(h0) | pe);
                    astore64(exg + (size_t)(r & 3) * LS_STRIDE
                                 + 2 * ok + (bb >> 1), u);
                }
            }
        }

        // ---- phase 2: stage h1(r-2) (staggered poll) ----
        if (r == 1) {
#pragma unroll
            for (int k = 0; k < 4; ++k)
                s1[tid + 512 * k] = make_float2(0.f, 0.f);
        } else if (r >= 2) {
            const unsigned long long* pl = exg + (size_t)(4 + sl) * LS_STRIDE;
            unsigned pend = 3u;
            u32x4 w0v, w1v;
            do {
                apoll2(pl + c0, pl + c1, w0v, w1v);
                if ((pend & 1u) && epok4(w0v, eb)) {
                    s1[tid]        = make_float2(
                        __uint_as_float(w0v[0] & PAYMASK),
                        __uint_as_float(w0v[1] & PAYMASK));
                    s1[1024 + tid] = make_float2(
                        __uint_as_float(w0v[2] & PAYMASK),
                        __uint_as_float(w0v[3] & PAYMASK));
                    pend &= ~1u;
                }
                if ((pend & 2u) && epok4(w1v, eb)) {
                    s1[512 + tid]  = make_float2(
                        __uint_as_float(w1v[0] & PAYMASK),
                        __uint_as_float(w1v[1] & PAYMASK));
                    s1[1536 + tid] = make_float2(
                        __uint_as_float(w1v[2] & PAYMASK),
                        __uint_as_float(w1v[3] & PAYMASK));
                    pend &= ~2u;
                }
            } while (pend);
        }
        __syncthreads();   // barrier 2: h1 staged -> passB may read

        // ---- pass B: v = Wih1 h0(r-1) + Whh1 h1(r-2); fold; h1(r-1) ----
        if (r >= 1) {
            float v[16] = {};
#pragma unroll
            for (int q = 0; q < 16; ++q) {
                const float2 a0 = s0[q * 64 + kg];
                const float2 a1 = s0[1024 + q * 64 + kg];
                const float2 c0f = s1[q * 64 + kg];
                const float2 c1f = s1[1024 + q * 64 + kg];
#pragma unroll
                for (int i = 0; i < 4; ++i) {
                    const float fb = wx[i][q];
                    v[i*4+0] += fb * a0.x; v[i*4+1] += fb * a0.y;
                    v[i*4+2] += fb * a1.x; v[i*4+3] += fb * a1.y;
                    const float fc = wh[i][q];
                    v[i*4+0] += fc * c0f.x; v[i*4+1] += fc * c0f.y;
                    v[i*4+2] += fc * c1f.x; v[i*4+3] += fc * c1f.y;
                }
            }
            const float r1 = fold16(v, kg);
            float h1 = 0.f;
            if (kg < 16) h1 = tanhf(r1 + bsum);
            const float h1p = __shfl_xor(h1, 1, 64);
            if (kg < 16) *px1 = h1;     // overwrites consumed xp0 (b, r-1, ok)
            if (kg < 16 && (bb & 1) == 0) {
                const unsigned pe = (((unsigned)r >> 2) & 1u) << 30;
                const unsigned long long u =
                    ((unsigned long long)(__float_as_uint(h1p) | pe) << 32) |
                    (unsigned long long)(__float_as_uint(h1) | pe);
                astore64(exg + (size_t)(4 + (r & 3)) * LS_STRIDE
                             + 2 * ok + (bb >> 1), u);
            }
            px1 += HID_;
        }
        // no trailing barrier: double-buffered planes (see header)
    }
}

extern "C" void kernel_launch(void* const* d_in, const int* in_sizes, int n_in,
                              void* d_out, int out_size, void* d_ws, size_t ws_size,
                              hipStream_t stream)
{
    const int*   tokens = (const int*)  d_in[0];
    const float* emb    = (const float*)d_in[1];
    const float* W_ih0  = (const float*)d_in[2];
    const float* W_hh0  = (const float*)d_in[3];
    const float* b_ih0  = (const float*)d_in[4];
    const float* b_hh0  = (const float*)d_in[5];
    const float* W_ih1  = (const float*)d_in[6];
    const float* W_hh1  = (const float*)d_in[7];
    const float* b_ih1  = (const float*)d_in[8];
    const float* b_hh1  = (const float*)d_in[9];
    const float* W_out  = (const float*)d_in[10];
    const float* b_out  = (const float*)d_in[11];
    float* out = (float*)d_out;

    float* buf = (float*)d_ws;                            // 64 MiB: xp0 -> h1
    unsigned long long* ex = (unsigned long long*)d_out;  // 1 MB exchange

    // 96 KB dynamic LDS -> exactly 1 WG/CU (256 WGs co-resident on 256 CUs)
    const size_t scan_lds = 98304;
    hipFuncSetAttribute((const void*)rnn_fused,
                        hipFuncAttributeMaxDynamicSharedMemorySize, (int)scan_lds);

    // 1) xp0 = gather(emb,tokens) @ W_ih0^T + b_ih0 + b_hh0  -> buf
    gemm_bias<<<dim3(HID_ / 64, M_ / 128), 256, 0, stream>>>(
        emb, tokens, W_ih0, b_ih0, b_hh0, buf, M_, EMB_, HID_);

    // 2) pre-fill exchange epochs
    fill_poison<<<EX_TOTAL / 256, 256, 0, stream>>>(ex, EX_TOTAL);

    // 3) fused 2-layer skewed scan: xp0 consumed, h1 left in buf
    rnn_fused<<<256, 512, scan_lds, stream>>>(
        W_hh0, W_hh1, W_ih1, b_ih1, b_hh1, buf, ex);

    // 4) out = h1 @ W_out^T + b_out (fully rewrites d_out incl. ex region)
    gemm_bias<<<dim3(LAB_ / 64, M_ / 128), 256, 0, stream>>>(
        buf, nullptr, W_out, b_out, nullptr, out, M_, HID_, LAB_);
}

// Round 9
// 3132.398 us; speedup vs baseline: 3.8414x; 1.0401x over previous
//
#include <hip/hip_runtime.h>
#include <math.h>

#define B_    32
#define S_    512
#define EMB_  512
#define HID_  1024
#define LAB_  64
#define M_    (B_ * S_)

// ---------------------------------------------------------------------------
// R18: fused pipeline with ONE handshake per round. R17 post-mortem: round =
// 14k cyc = 2 sequential handshakes (7k each, visibility-latency floor) on
// top of ~4k compute. R18 merges the two polls into one phase and buys
// grace so publishes are already visible when polled:
//   round r:  passA: h0(r)   = tanh(xp0(r) + Whh0 h0(r-1))        [r<512]
//             passB: h1(r-2) = tanh(Wih1 h0(r-2) + Whh1 h1(r-3)+b) [r>=2]
// Polled at round r: h0(r-1) (published mid-round r-1, grace ~ half round)
// and h1(r-3) (published end of round r-2, grace ~ 1.5 rounds). One poll
// phase + ONE barrier per round; handshake latency is hidden under the
// grace => per-round cost ~ compute + one sweep RT.
//
// LDS: h0 TRIPLE-buffered (passB(r) reads h0(r-2) one round after staging):
//   h0(u) staged at round u+1 into plane[(u+1)%3]; passA(r) reads
//   plane[r%3] (h0(r-1)); passB(r) reads plane[(r+2)%3] (= (r-1)%3,
//   h0(r-2)); stage(r+1) writes plane[(r+1)%3] -- disjoint from both read
//   planes of round r, and round-(r+1) readers are behind BAR(r+1). h1
//   double-buffered: stage(r) writes s1[r&1] (h1(r-3)), read by passB(r);
//   overwrite at r+2 is ordered by BAR(r+1) (slow reader's passB(r) reads
//   precede its BAR(r+1) arrival; fast writer's stage(r+2) follows it).
// Total 5 planes x 16 KB = 80 KB < 96 KB -> still 1 WG/CU.
//
// Exchange (epoch-bit, depth-4 slots, u64 = {enc(h[b0,n]), enc(h[b1,n])},
// enc = bits | epoch<<30; tanh => bit30 always 0):
//   h0(u): publish round u (passA) -> slot u&3, epoch (u>>2)&1;
//          consumed at round u+1.
//   h1(u): publish round u+2 (passB) -> slot u&3, epoch (u>>2)&1;
//          consumed at round u+3.
//   Skew<=1 round (staging r needs ALL WGs' round-(r-1) publishes) => when
//   any consumer awaits slot content of timestep u, no producer can yet
//   have published timestep u+4 into that slot (would require the waiting
//   WG to be 2+ rounds behind) => only possible stale content is u-4 =
//   opposite epoch. First poll of EVERY address expects epoch 0 => uniform
//   NANPAT (bit30=1) fill; no special case.
//
// History: R9 7.9k/step congested; R10 wbl2 6x; R11 +hops 1.5x; R12 L2
// pathology 130x; R14 7.4k/step = latency floor; R16 fused 16k/round;
// R17 split-barrier 14k/round = 2x floor. R18 hides the floor under grace.
// ---------------------------------------------------------------------------
#define SLOT_U64   2048                   // per (layer,slot,group)
#define LS_STRIDE  (8 * SLOT_U64)         // per (layer,slot)
#define EX_TOTAL   (2 * 4 * LS_STRIDE)    // 131072 u64 = 1 MB
#define EPBIT      0x40000000u
#define NANPAT64   0x7FC000007FC00000ULL  // epoch-1-looking fill
#define PAYMASK    0xBFFFFFFFu

typedef unsigned int u32x4 __attribute__((ext_vector_type(4)));

__device__ __forceinline__ void astore64(unsigned long long* p, unsigned long long v) {
    __hip_atomic_store(p, v, __ATOMIC_RELAXED, __HIP_MEMORY_SCOPE_AGENT);
}
// two 16B agent-scope polls in one issue window (one RT per sweep)
__device__ __forceinline__ void apoll2(const unsigned long long* q0,
                                       const unsigned long long* q1,
                                       u32x4& w0, u32x4& w1) {
    asm volatile(
        "global_load_dwordx4 %0, %2, off sc1\n\t"
        "global_load_dwordx4 %1, %3, off sc1\n\t"
        "s_waitcnt vmcnt(0)"
        : "=&v"(w0), "=&v"(w1)
        : "v"(q0), "v"(q1)
        : "memory");
}
__device__ __forceinline__ bool epok4(u32x4 v, unsigned eb) {
    return ((((v[0] ^ eb) | (v[1] ^ eb)) | ((v[2] ^ eb) | (v[3] ^ eb)))
            & EPBIT) == 0;
}
// 16-acc halving-tree: after masks 1,2,4,8 + 16,32, lane p holds out(p&15).
__device__ __forceinline__ float fold16(float* v, int kg) {
#pragma unroll
    for (int st = 0; st < 4; ++st) {
        const int m  = 1 << st;
        const int nh = 8 >> st;
        const bool hi = (kg & m) != 0;
#pragma unroll
        for (int j = 0; j < 8; ++j) {
            if (j < nh) {
                const float a0 = v[2*j], a1 = v[2*j+1];
                const float got = __shfl_xor(hi ? a0 : a1, m, 64);
                v[j] = (hi ? a1 : a0) + got;
            }
        }
    }
    float r = v[0];
    r += __shfl_xor(r, 16, 64);
    r += __shfl_xor(r, 32, 64);
    return r;
}

// ---------------------------------------------------------------------------
// fp32 tiled GEMM (unchanged): BM=128, BN=64, BK=16, 256 thr, 8x4/thread.
// ---------------------------------------------------------------------------
__global__ __launch_bounds__(256) void gemm_bias(
    const float* __restrict__ A, const int* __restrict__ tokens,
    const float* __restrict__ W, const float* __restrict__ bias,
    const float* __restrict__ bias2, float* __restrict__ C,
    int M, int K, int N)
{
    __shared__ float As[128][17];
    __shared__ float Ws[64][17];

    const int tid = threadIdx.x;
    const int tx  = tid & 15;
    const int ty  = tid >> 4;
    const int n0  = blockIdx.x * 64;
    const int m0  = blockIdx.y * 128;

    const int lr  = tid >> 2;
    const int lk  = (tid & 3) << 2;

    const int ar0 = tokens ? tokens[m0 + lr]      : (m0 + lr);
    const int ar1 = tokens ? tokens[m0 + 64 + lr] : (m0 + 64 + lr);
    const float* __restrict__ arow0 = A + (size_t)ar0 * K;
    const float* __restrict__ arow1 = A + (size_t)ar1 * K;
    const float* __restrict__ wrow  = W + (size_t)(n0 + lr) * K;

    float bs[4];
#pragma unroll
    for (int j = 0; j < 4; ++j) {
        int n = n0 + tx * 4 + j;
        bs[j] = bias[n] + (bias2 ? bias2[n] : 0.0f);
    }

    float acc[8][4] = {};

    for (int k0 = 0; k0 < K; k0 += 16) {
        const float4 a0 = *(const float4*)(arow0 + k0 + lk);
        const float4 a1 = *(const float4*)(arow1 + k0 + lk);
        const float4 wv = *(const float4*)(wrow  + k0 + lk);
        __syncthreads();
        As[lr][lk + 0] = a0.x; As[lr][lk + 1] = a0.y;
        As[lr][lk + 2] = a0.z; As[lr][lk + 3] = a0.w;
        As[64 + lr][lk + 0] = a1.x; As[64 + lr][lk + 1] = a1.y;
        As[64 + lr][lk + 2] = a1.z; As[64 + lr][lk + 3] = a1.w;
        Ws[lr][lk + 0] = wv.x; Ws[lr][lk + 1] = wv.y;
        Ws[lr][lk + 2] = wv.z; Ws[lr][lk + 3] = wv.w;
        __syncthreads();

#pragma unroll
        for (int kk = 0; kk < 16; ++kk) {
            float b[4], a[8];
#pragma unroll
            for (int j = 0; j < 4; ++j) b[j] = Ws[tx * 4 + j][kk];
#pragma unroll
            for (int i = 0; i < 8; ++i) a[i] = As[ty * 8 + i][kk];
#pragma unroll
            for (int i = 0; i < 8; ++i)
#pragma unroll
                for (int j = 0; j < 4; ++j)
                    acc[i][j] += a[i] * b[j];
        }
    }

#pragma unroll
    for (int i = 0; i < 8; ++i) {
        const int m = m0 + ty * 8 + i;
        float4 v;
        v.x = acc[i][0] + bs[0];
        v.y = acc[i][1] + bs[1];
        v.z = acc[i][2] + bs[2];
        v.w = acc[i][3] + bs[3];
        *(float4*)(C + (size_t)m * N + n0 + tx * 4) = v;
    }
}

// ---------------------------------------------------------------------------
// Fill: NANPAT (epoch-1-look) everywhere; every first poll expects epoch 0.
// ---------------------------------------------------------------------------
__global__ __launch_bounds__(256) void fill_poison(unsigned long long* p, int n)
{
    const int i = blockIdx.x * 256 + threadIdx.x;
    if (i < n) p[i] = NANPAT64;
}

// ---------------------------------------------------------------------------
// Fused 2-layer scan, 2-round L1 skew. Weights: 3 x (4n x 16q) = 192 regs.
// Partition: slice s = wg>>3 (32 neurons), group g = wg&7 (4 batches).
// Rounds r = 0..513. One poll phase + one barrier per round.
// ---------------------------------------------------------------------------
__global__ __launch_bounds__(512, 2) void rnn_fused(
    const float* __restrict__ Whh0, const float* __restrict__ Whh1,
    const float* __restrict__ Wih1, const float* __restrict__ b_ih1,
    const float* __restrict__ b_hh1, float* __restrict__ xb,
    unsigned long long* __restrict__ ex)
{
    extern __shared__ float smem[];
    float2* hb = (float2*)smem;        // h0: planes 0..2; h1: planes 3..4

    const int wg  = blockIdx.x;
    const int g   = wg & 7;            // group: batches g*4..g*4+3
    const int s   = wg >> 3;           // slice: neurons s*32..s*32+31
    const int tid = threadIdx.x;       // 0..511
    const int j8  = tid >> 6;          // wave: neurons s*32 + j8*4 ..+3
    const int kg  = tid & 63;          // lane; k = kg + 64q
    const int b0  = g * 4;

    // weights: 4 neurons x 16 strided k, three matrices (lane-coalesced)
    float w0[4][16], wx[4][16], wh[4][16];
    {
        const size_t base = (size_t)(s * 32 + j8 * 4) * HID_ + kg;
#pragma unroll
        for (int i = 0; i < 4; ++i)
#pragma unroll
            for (int q = 0; q < 16; ++q) {
                const size_t o = base + (size_t)i * HID_ + (size_t)q * 64;
                w0[i][q] = Whh0[o];
                wx[i][q] = Wih1[o];
                wh[i][q] = Whh1[o];
            }
    }

    const int i4 = (kg >> 2) & 3;      // output neuron (lanes<16)
    const int bb = kg & 3;             // output batch  (lanes<16)
    const int ok = s * 32 + j8 * 4 + i4;
    float bsum = 0.f;
    if (kg < 16) bsum = b_ih1[ok] + b_hh1[ok];

    float* px0 = xb + ((size_t)(b0 + bb) * S_) * HID_ + ok;  // xp0 read (b,r)
    float* px1 = px0;                             // h1 write (b, r-2)

    unsigned long long* const exg = ex + (size_t)g * SLOT_U64;
    // consumer 16B lines: neurons tid and 512+tid (words 2n, 2n+1)
    const int c0 = 2 * tid, c1 = 1024 + 2 * tid;

    for (int r = 0; r <= S_ + 1; ++r) {
        // ---- xp0 prefetch (overlaps the poll) ----
        float xpv = 0.f;
        if (kg < 16 && r < S_) xpv = *px0;
        px0 += HID_;

        float2* sA = hb + (size_t)(r % 3) * 2048;        // h0(r-1) stage
        float2* sP = hb + (size_t)((r + 2) % 3) * 2048;  // h0(r-2) (passB)
        float2* s1 = hb + (size_t)(3 + (r & 1)) * 2048;  // h1(r-3) stage

        // ---- single poll phase: h0(r-1) [r in 1..512], h1(r-3) [r>=3] ----
        if (r == 0) {
#pragma unroll
            for (int k = 0; k < 4; ++k)
                sA[tid + 512 * k] = make_float2(0.f, 0.f);
        }
        if (r == 2) {
#pragma unroll
            for (int k = 0; k < 4; ++k)
                s1[tid + 512 * k] = make_float2(0.f, 0.f);
        }
        {
            unsigned pend = ((r >= 1 && r <= S_) ? 3u : 0u)
                          | ((r >= 3) ? 0xCu : 0u);
            if (pend) {
                const unsigned long long* pl0 =
                    exg + (size_t)((r - 1) & 3) * LS_STRIDE;
                const unsigned long long* pl1 =
                    exg + (size_t)(4 + ((r - 3) & 3)) * LS_STRIDE;
                const unsigned eb0 = ((((unsigned)(r - 1)) >> 2) & 1u) << 30;
                const unsigned eb1 = ((((unsigned)(r - 3)) >> 2) & 1u) << 30;
                u32x4 a0, a1, d0, d1;
                do {
                    if (pend & 3u) {
                        apoll2(pl0 + c0, pl0 + c1, a0, a1);
                        if ((pend & 1u) && epok4(a0, eb0)) {
                            sA[tid]        = make_float2(
                                __uint_as_float(a0[0] & PAYMASK),
                                __uint_as_float(a0[1] & PAYMASK));
                            sA[1024 + tid] = make_float2(
                                __uint_as_float(a0[2] & PAYMASK),
                                __uint_as_float(a0[3] & PAYMASK));
                            pend &= ~1u;
                        }
                        if ((pend & 2u) && epok4(a1, eb0)) {
                            sA[512 + tid]  = make_float2(
                                __uint_as_float(a1[0] & PAYMASK),
                                __uint_as_float(a1[1] & PAYMASK));
                            sA[1536 + tid] = make_float2(
                                __uint_as_float(a1[2] & PAYMASK),
                                __uint_as_float(a1[3] & PAYMASK));
                            pend &= ~2u;
                        }
                    }
                    if (pend & 0xCu) {
                        apoll2(pl1 + c0, pl1 + c1, d0, d1);
                        if ((pend & 4u) && epok4(d0, eb1)) {
                            s1[tid]        = make_float2(
                                __uint_as_float(d0[0] & PAYMASK),
                                __uint_as_float(d0[1] & PAYMASK));
                            s1[1024 + tid] = make_float2(
                                __uint_as_float(d0[2] & PAYMASK),
                                __uint_as_float(d0[3] & PAYMASK));
                            pend &= ~4u;
                        }
                        if ((pend & 8u) && epok4(d1, eb1)) {
                            s1[512 + tid]  = make_float2(
                                __uint_as_float(d1[0] & PAYMASK),
                                __uint_as_float(d1[1] & PAYMASK));
                            s1[1536 + tid] = make_float2(
                                __uint_as_float(d1[2] & PAYMASK),
                                __uint_as_float(d1[3] & PAYMASK));
                            pend &= ~8u;
                        }
                    }
                } while (pend);
            }
        }
        __syncthreads();   // the ONE barrier per round

        // ---- pass A: h0(r) = tanh(xp0(r) + Whh0 h0(r-1)); publish ----
        if (r < S_) {
            float v[16] = {};
#pragma unroll
            for (int q = 0; q < 16; ++q) {
                const float2 a0 = sA[q * 64 + kg];          // batches 0,1
                const float2 a1 = sA[1024 + q * 64 + kg];   // batches 2,3
#pragma unroll
                for (int i = 0; i < 4; ++i) {
                    const float fa = w0[i][q];
                    v[i*4+0] += fa * a0.x; v[i*4+1] += fa * a0.y;
                    v[i*4+2] += fa * a1.x; v[i*4+3] += fa * a1.y;
                }
            }
            const float r0 = fold16(v, kg);
            float h0 = 0.f;
            if (kg < 16) h0 = tanhf(xpv + r0);
            const float h0p = __shfl_xor(h0, 1, 64);   // partner batch
            if (kg < 16 && (bb & 1) == 0) {
                const unsigned pe = (((unsigned)r >> 2) & 1u) << 30;
                const unsigned long long u =
                    ((unsigned long long)(__float_as_uint(h0p) | pe) << 32) |
                    (unsigned long long)(__float_as_uint(h0) | pe);
                astore64(exg + (size_t)(r & 3) * LS_STRIDE
                             + 2 * ok + (bb >> 1), u);
            }
        }

        // ---- pass B: h1(r-2) = tanh(Wih1 h0(r-2) + Whh1 h1(r-3) + b) ----
        if (r >= 2) {
            float v[16] = {};
#pragma unroll
            for (int q = 0; q < 16; ++q) {
                const float2 a0 = sP[q * 64 + kg];          // h0(r-2)
                const float2 a1 = sP[1024 + q * 64 + kg];
                const float2 c0f = s1[q * 64 + kg];         // h1(r-3)
                const float2 c1f = s1[1024 + q * 64 + kg];
#pragma unroll
                for (int i = 0; i < 4; ++i) {
                    const float fb = wx[i][q];
                    v[i*4+0] += fb * a0.x; v[i*4+1] += fb * a0.y;
                    v[i*4+2] += fb * a1.x; v[i*4+3] += fb * a1.y;
                    const float fc = wh[i][q];
                    v[i*4+0] += fc * c0f.x; v[i*4+1] += fc * c0f.y;
                    v[i*4+2] += fc * c1f.x; v[i*4+3] += fc * c1f.y;
                }
            }
            const float r1 = fold16(v, kg);
            float h1 = 0.f;
            if (kg < 16) h1 = tanhf(r1 + bsum);
            const float h1p = __shfl_xor(h1, 1, 64);
            if (kg < 16) *px1 = h1;     // h1(r-2) overwrites consumed xp0
            if (kg < 16 && (bb & 1) == 0) {
                const unsigned pe = (((unsigned)(r - 2) >> 2) & 1u) << 30;
                const unsigned long long u =
                    ((unsigned long long)(__float_as_uint(h1p) | pe) << 32) |
                    (unsigned long long)(__float_as_uint(h1) | pe);
                astore64(exg + (size_t)(4 + ((r - 2) & 3)) * LS_STRIDE
                             + 2 * ok + (bb >> 1), u);
            }
            px1 += HID_;
        }
        // no trailing barrier: plane rotation proves no WAR (see header)
    }
}

extern "C" void kernel_launch(void* const* d_in, const int* in_sizes, int n_in,
                              void* d_out, int out_size, void* d_ws, size_t ws_size,
                              hipStream_t stream)
{
    const int*   tokens = (const int*)  d_in[0];
    const float* emb    = (const float*)d_in[1];
    const float* W_ih0  = (const float*)d_in[2];
    const float* W_hh0  = (const float*)d_in[3];
    const float* b_ih0  = (const float*)d_in[4];
    const float* b_hh0  = (const float*)d_in[5];
    const float* W_ih1  = (const float*)d_in[6];
    const float* W_hh1  = (const float*)d_in[7];
    const float* b_ih1  = (const float*)d_in[8];
    const float* b_hh1  = (const float*)d_in[9];
    const float* W_out  = (const float*)d_in[10];
    const float* b_out  = (const float*)d_in[11];
    float* out = (float*)d_out;

    float* buf = (float*)d_ws;                            // 64 MiB: xp0 -> h1
    unsigned long long* ex = (unsigned long long*)d_out;  // 1 MB exchange

    // 96 KB dynamic LDS -> exactly 1 WG/CU (256 WGs co-resident on 256 CUs)
    const size_t scan_lds = 98304;
    hipFuncSetAttribute((const void*)rnn_fused,
                        hipFuncAttributeMaxDynamicSharedMemorySize, (int)scan_lds);

    // 1) xp0 = gather(emb,tokens) @ W_ih0^T + b_ih0 + b_hh0  -> buf
    gemm_bias<<<dim3(HID_ / 64, M_ / 128), 256, 0, stream>>>(
        emb, tokens, W_ih0, b_ih0, b_hh0, buf, M_, EMB_, HID_);

    // 2) pre-fill exchange epochs
    fill_poison<<<EX_TOTAL / 256, 256, 0, stream>>>(ex, EX_TOTAL);

    // 3) fused 2-layer skewed scan: xp0 consumed, h1 left in buf
    rnn_fused<<<256, 512, scan_lds, stream>>>(
        W_hh0, W_hh1, W_ih1, b_ih1, b_hh1, buf, ex);

    // 4) out = h1 @ W_out^T + b_out (fully rewrites d_out incl. ex region)
    gemm_bias<<<dim3(LAB_ / 64, M_ / 128), 256, 0, stream>>>(
        buf, nullptr, W_out, b_out, nullptr, out, M_, HID_, LAB_);
}